// Round 1
// baseline (1267.758 us; speedup 1.0000x reference)
//
#include <hip/hip_runtime.h>
#include <math.h>

#define D_   16
#define H_   56
#define W_   56
#define CIN  32
#define COUT 64
#define KPTS 27
#define NCH  81                  // 3*KPTS offset channels
#define NP   (D_*H_*W_)          // 50176 output positions (== 196*256)
#define CHW  (D_*H_*W_)          // per-channel plane size

static __device__ __forceinline__ int iclamp(int v, int lo, int hi) {
    return v < lo ? lo : (v > hi ? hi : v);
}

// ---------------------------------------------------------------------------
// Tiny prep: transpose weights so the innermost (register-unrolled) index is
// contiguous in memory -> uniform s_load_dwordx16 runs.
//   weight [COUT][CIN][27]  -> wT  [27][CIN][COUT]
//   offw   [81][CIN][27]    -> owT [27][CIN][81]
// ---------------------------------------------------------------------------
__global__ __launch_bounds__(256) void k_transpose(const float* __restrict__ w,
                                                   const float* __restrict__ ow,
                                                   float* __restrict__ wT,
                                                   float* __restrict__ owT) {
    int i = blockIdx.x * 256 + threadIdx.x;
    if (i < COUT * CIN * KPTS) {
        int k = i % KPTS;
        int c = (i / KPTS) % CIN;
        int o = i / (KPTS * CIN);
        wT[(k * CIN + c) * COUT + o] = w[i];
    }
    if (i < NCH * CIN * KPTS) {
        int k  = i % KPTS;
        int c  = (i / KPTS) % CIN;
        int ch = i / (KPTS * CIN);
        owT[(k * CIN + c) * NCH + ch] = ow[i];
    }
}

// ---------------------------------------------------------------------------
// Kernel A: dense 3x3x3 conv producing the 81 offset channels, fused with the
// base-grid addition. Writes absolute sample coords as [3][27][NP] (z,y,x).
// One thread per output position; 81 fp32 accumulators in VGPRs.
// ---------------------------------------------------------------------------
__global__ __launch_bounds__(256) void k_offsets(const float* __restrict__ x,
                                                 const float* __restrict__ owT,
                                                 const float* __restrict__ offb,
                                                 float* __restrict__ coords) {
    const int p  = blockIdx.x * 256 + threadIdx.x;   // grid sized exactly
    const int ox = p % W_;
    const int t  = p / W_;
    const int oy = t % H_;
    const int oz = t / H_;

    float acc[NCH];
#pragma unroll
    for (int ch = 0; ch < NCH; ++ch) acc[ch] = offb[ch];

    for (int kz = 0; kz < 3; ++kz) {
        const int  zi = oz - 1 + kz;
        const bool zv = ((unsigned)zi < (unsigned)D_);
        for (int ky = 0; ky < 3; ++ky) {
            const int  yi = oy - 1 + ky;
            const bool yv = ((unsigned)yi < (unsigned)H_);
            for (int kx = 0; kx < 3; ++kx) {
                const int  xi = ox - 1 + kx;
                const bool v  = zv && yv && ((unsigned)xi < (unsigned)W_);
                const int  kpt = (kz * 3 + ky) * 3 + kx;
                const float* xp = x + ((zi * H_ + yi) * W_ + xi);
                const float* wp = owT + kpt * CIN * NCH;
                for (int c = 0; c < CIN; ++c) {
                    const float xv = v ? xp[c * CHW] : 0.0f;
#pragma unroll
                    for (int ch = 0; ch < NCH; ++ch)
                        acc[ch] += wp[c * NCH + ch] * xv;
                }
            }
        }
    }

    // coords = offset + base grid  (d: 0=z, 1=y, 2=x; channel = k*3+d)
#pragma unroll
    for (int k = 0; k < KPTS; ++k) {
        const int kz = k / 9, ky = (k / 3) % 3, kx = k % 3;
        coords[(0 * KPTS + k) * NP + p] = acc[k * 3 + 0] + (float)(oz - 1 + kz);
        coords[(1 * KPTS + k) * NP + p] = acc[k * 3 + 1] + (float)(oy - 1 + ky);
        coords[(2 * KPTS + k) * NP + p] = acc[k * 3 + 2] + (float)(ox - 1 + kx);
    }
}

// ---------------------------------------------------------------------------
// Kernel B: fused trilinear sampling + channel contraction + bias.
// One thread per output position; 64 fp32 accumulators. For each kernel point:
// compute 8 corner weights/indices once, then per input channel gather 8
// values, reduce, and do 64 FMAs against the (uniform, scalarized) weights.
// ---------------------------------------------------------------------------
__global__ __launch_bounds__(256) void k_dconv(const float* __restrict__ x,
                                               const float* __restrict__ coords,
                                               const float* __restrict__ wT,
                                               const float* __restrict__ bias,
                                               float* __restrict__ out) {
    const int p = blockIdx.x * 256 + threadIdx.x;

    float acc[COUT];
#pragma unroll
    for (int o = 0; o < COUT; ++o) acc[o] = 0.0f;

    for (int k = 0; k < KPTS; ++k) {
        const float cz = coords[(0 * KPTS + k) * NP + p];
        const float cy = coords[(1 * KPTS + k) * NP + p];
        const float cx = coords[(2 * KPTS + k) * NP + p];

        const float zf = floorf(cz), yf = floorf(cy), xf = floorf(cx);
        const float fz = cz - zf, fy = cy - yf, fx = cx - xf;
        const int z0 = (int)zf, y0 = (int)yf, x0 = (int)xf;

        float w8[8];
        int   idx8[8];
#pragma unroll
        for (int j = 0; j < 8; ++j) {
            const int dz = j >> 2, dy = (j >> 1) & 1, dx = j & 1;
            const int zi = z0 + dz, yi = y0 + dy, xi = x0 + dx;
            const bool v = ((unsigned)zi < (unsigned)D_) &&
                           ((unsigned)yi < (unsigned)H_) &&
                           ((unsigned)xi < (unsigned)W_);
            const float wz = dz ? fz : 1.0f - fz;
            const float wy = dy ? fy : 1.0f - fy;
            const float wx = dx ? fx : 1.0f - fx;
            w8[j] = v ? wz * wy * wx : 0.0f;
            const int zc = iclamp(zi, 0, D_ - 1);
            const int yc = iclamp(yi, 0, H_ - 1);
            const int xc = iclamp(xi, 0, W_ - 1);
            idx8[j] = (zc * H_ + yc) * W_ + xc;
        }

        const float* wp = wT + k * CIN * COUT;
        for (int c = 0; c < CIN; ++c) {
            const float* xc = x + c * CHW;
            float sv = 0.0f;
#pragma unroll
            for (int j = 0; j < 8; ++j) sv += w8[j] * xc[idx8[j]];
#pragma unroll
            for (int o = 0; o < COUT; ++o)
                acc[o] += wp[c * COUT + o] * sv;
        }
    }

#pragma unroll
    for (int o = 0; o < COUT; ++o)
        out[o * NP + p] = acc[o] + bias[o];
}

// ---------------------------------------------------------------------------
extern "C" void kernel_launch(void* const* d_in, const int* in_sizes, int n_in,
                              void* d_out, int out_size, void* d_ws, size_t ws_size,
                              hipStream_t stream) {
    const float* x    = (const float*)d_in[0];  // [32,16,56,56]
    const float* offw = (const float*)d_in[1];  // [81,32,3,3,3]
    const float* offb = (const float*)d_in[2];  // [81]
    const float* wgt  = (const float*)d_in[3];  // [64,32,3,3,3]
    const float* bias = (const float*)d_in[4];  // [64]
    float* out = (float*)d_out;                 // [64,16,56,56]

    float* ws     = (float*)d_ws;
    float* coords = ws;                         // 3*27*NP floats (~16.3 MB)
    float* wT     = coords + 3 * KPTS * NP;     // 27*32*64
    float* owT    = wT + KPTS * CIN * COUT;     // 27*32*81

    const int n_tr = NCH * CIN * KPTS;          // 69984 (covers both transposes)
    hipLaunchKernelGGL(k_transpose, dim3((n_tr + 255) / 256), dim3(256), 0, stream,
                       wgt, offw, wT, owT);
    hipLaunchKernelGGL(k_offsets, dim3(NP / 256), dim3(256), 0, stream,
                       x, owT, offb, coords);
    hipLaunchKernelGGL(k_dconv, dim3(NP / 256), dim3(256), 0, stream,
                       x, coords, wT, bias, out);
}